// Round 1
// baseline (63.323 us; speedup 1.0000x reference)
//
#include <hip/hip_runtime.h>

// DCTProcessor: 8x8 block DCT (as the reference einsum computes it:
// out = D @ X @ D, NOT D @ X @ D^T), drop DC, global max, per-(b,c)
// 64-bin histogram normalized by H*W.
//
// Fixed shapes per reference: B=32, C=3, H=W=512 -> BC=96, 4096 blocks/(b,c),
// 393216 blocks total, out = 32*192 = 6144 floats.

#define NUM_BINS 64
#define HREP 16          // LDS histogram replicas (cuts same-address atomic serialization)

__device__ __forceinline__ void load_block(const float* __restrict__ p, float* blk) {
    #pragma unroll
    for (int r = 0; r < 8; ++r) {
        float4 a = *reinterpret_cast<const float4*>(p + (size_t)r * 512);
        float4 b = *reinterpret_cast<const float4*>(p + (size_t)r * 512 + 4);
        blk[r*8+0]=a.x; blk[r*8+1]=a.y; blk[r*8+2]=a.z; blk[r*8+3]=a.w;
        blk[r*8+4]=b.x; blk[r*8+5]=b.y; blk[r*8+6]=b.z; blk[r*8+7]=b.w;
    }
}

// ---------------- Pass 1: global max of |coeff| (DC dropped) ----------------
__global__ __launch_bounds__(256) void dct_max_kernel(
    const float* __restrict__ x, const float* __restrict__ basis,
    unsigned int* __restrict__ gmax)
{
    __shared__ float D[64];
    __shared__ float wred[4];
    if (threadIdx.x < 64) D[threadIdx.x] = basis[threadIdx.x];
    __syncthreads();

    int tid = blockIdx.x * 256 + threadIdx.x;   // one 8x8 block per thread
    int bc  = tid >> 12;                        // tid / 4096
    int n   = tid & 4095;
    int hb  = n >> 6, wb = n & 63;
    const float* p = x + ((size_t)bc << 18) + ((size_t)(hb * 8) << 9) + (size_t)(wb * 8);

    float blk[64];
    load_block(p, blk);

    float m = 0.0f;
    #pragma unroll
    for (int i = 0; i < 8; ++i) {
        float t[8];
        #pragma unroll
        for (int k = 0; k < 8; ++k) {
            float s = 0.0f;
            #pragma unroll
            for (int j = 0; j < 8; ++j) s = fmaf(D[i*8+j], blk[j*8+k], s);
            t[k] = s;
        }
        #pragma unroll
        for (int l = 0; l < 8; ++l) {
            float s = 0.0f;
            #pragma unroll
            for (int k = 0; k < 8; ++k) s = fmaf(t[k], D[k*8+l], s);  // basis[k,l]: einsum 'kl'
            if (i != 0 || l != 0) m = fmaxf(m, fabsf(s));
        }
    }

    // wave64 max reduce
    #pragma unroll
    for (int off = 32; off > 0; off >>= 1)
        m = fmaxf(m, __shfl_down(m, off, 64));
    if ((threadIdx.x & 63) == 0) wred[threadIdx.x >> 6] = m;
    __syncthreads();
    if (threadIdx.x == 0) {
        float mm = fmaxf(fmaxf(wred[0], wred[1]), fmaxf(wred[2], wred[3]));
        // mags are >= 0, so uint bit-pattern compare == float compare
        atomicMax(gmax, __float_as_uint(mm));
    }
}

// ---------------- Pass 2: per-(b,c) histogram ----------------
__global__ __launch_bounds__(256) void dct_hist_kernel(
    const float* __restrict__ x, const float* __restrict__ basis,
    const unsigned int* __restrict__ gmax, float* __restrict__ out)
{
    __shared__ float D[64];
    __shared__ unsigned int hist[NUM_BINS * HREP];   // 4 KiB
    if (threadIdx.x < 64) D[threadIdx.x] = basis[threadIdx.x];
    for (int i = threadIdx.x; i < NUM_BINS * HREP; i += 256) hist[i] = 0;
    __syncthreads();

    int bc      = blockIdx.x >> 2;      // 4 workgroups per (b,c)
    int quarter = blockIdx.x & 3;
    float hist_max = __uint_as_float(*gmax) * 1.1f;
    float scale    = (float)NUM_BINS / hist_max;
    int   sub      = threadIdx.x & (HREP - 1);

    for (int it = 0; it < 4; ++it) {
        int n  = quarter * 1024 + it * 256 + threadIdx.x;
        int hb = n >> 6, wb = n & 63;
        const float* p = x + ((size_t)bc << 18) + ((size_t)(hb * 8) << 9) + (size_t)(wb * 8);

        float blk[64];
        load_block(p, blk);

        #pragma unroll
        for (int i = 0; i < 8; ++i) {
            float t[8];
            #pragma unroll
            for (int k = 0; k < 8; ++k) {
                float s = 0.0f;
                #pragma unroll
                for (int j = 0; j < 8; ++j) s = fmaf(D[i*8+j], blk[j*8+k], s);
                t[k] = s;
            }
            #pragma unroll
            for (int l = 0; l < 8; ++l) {
                float s = 0.0f;
                #pragma unroll
                for (int k = 0; k < 8; ++k) s = fmaf(t[k], D[k*8+l], s);
                if (i != 0 || l != 0) {
                    float mag = fabsf(s);
                    int bin = (int)floorf(mag * scale);   // mag >= 0
                    bin = min(bin, NUM_BINS - 1);
                    atomicAdd(&hist[bin * HREP + sub], 1u);
                }
            }
        }
    }
    __syncthreads();

    if (threadIdx.x < NUM_BINS) {
        unsigned int c = 0;
        #pragma unroll
        for (int r = 0; r < HREP; ++r) c += hist[threadIdx.x * HREP + r];
        // counts <= 2^18, /2^18 -> dyadic, <=19 mantissa bits: 4-way float
        // atomic sum is exact => deterministic
        atomicAdd(&out[bc * NUM_BINS + threadIdx.x], (float)c * (1.0f / 262144.0f));
    }
}

extern "C" void kernel_launch(void* const* d_in, const int* in_sizes, int n_in,
                              void* d_out, int out_size, void* d_ws, size_t ws_size,
                              hipStream_t stream) {
    const float* x     = (const float*)d_in[0];
    const float* basis = (const float*)d_in[1];
    float* out         = (float*)d_out;
    unsigned int* gmax = (unsigned int*)d_ws;

    const int total_blocks = in_sizes[0] / 64;      // 393216
    const int bc           = in_sizes[0] / (512 * 512); // 96

    // zero the max slot and the output accumulators (graph-capture-safe)
    hipMemsetAsync(gmax, 0, sizeof(unsigned int), stream);
    hipMemsetAsync(out, 0, (size_t)out_size * sizeof(float), stream);

    dct_max_kernel<<<total_blocks / 256, 256, 0, stream>>>(x, basis, gmax);
    dct_hist_kernel<<<bc * 4, 256, 0, stream>>>(x, basis, gmax, out);
}

// Round 2
// 53.685 us; speedup vs baseline: 1.1795x; 1.1795x over previous
//
#include <hip/hip_runtime.h>

// DCTProcessor: 8x8 block DCT (as the reference einsum computes it:
// out = D @ X @ D, NOT D @ X @ D^T), drop DC, global max of |coeff|,
// per-(b,c) 64-bin histogram normalized by H*W.
//
// Fixed shapes per reference: B=32, C=3, H=W=512 -> BC=96, 4096 blocks/(b,c),
// 393216 blocks total, out = 32*192 = 6144 floats.
//
// Two kernels, zero memsets:
//  k1: one 8x8 block/thread, per-WG max -> plain store d_ws[wg] (no init
//      needed), first 24 WGs also zero d_out (6144 floats).
//  k2: 16 WGs per (b,c) (1536 total, 6/CU), one block/thread, reduce the
//      1536 partial maxima, replicated-LDS histogram, 64 float atomicAdds
//      per WG into d_out (counts/2^18 are dyadic -> sum exact+deterministic).

#define NUM_BINS 64
#define HREP 16          // LDS histogram replicas (cuts same-address atomic serialization)
#define NWG1 1536        // 393216 blocks / 256 threads

__device__ __forceinline__ void load_block(const float* __restrict__ p, float* blk) {
    #pragma unroll
    for (int r = 0; r < 8; ++r) {
        float4 a = *reinterpret_cast<const float4*>(p + (size_t)r * 512);
        float4 b = *reinterpret_cast<const float4*>(p + (size_t)r * 512 + 4);
        blk[r*8+0]=a.x; blk[r*8+1]=a.y; blk[r*8+2]=a.z; blk[r*8+3]=a.w;
        blk[r*8+4]=b.x; blk[r*8+5]=b.y; blk[r*8+6]=b.z; blk[r*8+7]=b.w;
    }
}

// 2D DCT of one 8x8 block; returns max |coeff| excluding DC, and optionally
// emits each magnitude through the functor F (used by the histogram pass).
template <typename F>
__device__ __forceinline__ float dct_block(const float* __restrict__ D,
                                           const float* blk, F&& emit) {
    float m = 0.0f;
    #pragma unroll
    for (int i = 0; i < 8; ++i) {
        float t[8];
        #pragma unroll
        for (int k = 0; k < 8; ++k) {
            float s = 0.0f;
            #pragma unroll
            for (int j = 0; j < 8; ++j) s = fmaf(D[i*8+j], blk[j*8+k], s);
            t[k] = s;
        }
        #pragma unroll
        for (int l = 0; l < 8; ++l) {
            float s = 0.0f;
            #pragma unroll
            for (int k = 0; k < 8; ++k) s = fmaf(t[k], D[k*8+l], s);  // basis[k,l]: einsum 'kl'
            if (i != 0 || l != 0) {
                float mag = fabsf(s);
                m = fmaxf(m, mag);
                emit(mag);
            }
        }
    }
    return m;
}

struct NoEmit { __device__ void operator()(float) const {} };

// ---------------- Pass 1: per-WG max of |coeff| (DC dropped), zero d_out ----
__global__ __launch_bounds__(256) void dct_max_kernel(
    const float* __restrict__ x, const float* __restrict__ basis,
    float* __restrict__ wgmax, float* __restrict__ out)
{
    __shared__ float D[64];
    __shared__ float wred[4];
    if (threadIdx.x < 64) D[threadIdx.x] = basis[threadIdx.x];
    if (blockIdx.x < 24) out[blockIdx.x * 256 + threadIdx.x] = 0.0f;  // zero d_out
    __syncthreads();

    int tid = blockIdx.x * 256 + threadIdx.x;   // one 8x8 block per thread
    int bc  = tid >> 12;                        // tid / 4096
    int n   = tid & 4095;
    int hb  = n >> 6, wb = n & 63;
    const float* p = x + ((size_t)bc << 18) + ((size_t)(hb * 8) << 9) + (size_t)(wb * 8);

    float blk[64];
    load_block(p, blk);
    float m = dct_block(D, blk, NoEmit{});

    // wave64 max reduce
    #pragma unroll
    for (int off = 32; off > 0; off >>= 1)
        m = fmaxf(m, __shfl_down(m, off, 64));
    if ((threadIdx.x & 63) == 0) wred[threadIdx.x >> 6] = m;
    __syncthreads();
    if (threadIdx.x == 0)
        wgmax[blockIdx.x] = fmaxf(fmaxf(wred[0], wred[1]), fmaxf(wred[2], wred[3]));
}

// ---------------- Pass 2: per-(b,c) histogram ----------------
__global__ __launch_bounds__(256) void dct_hist_kernel(
    const float* __restrict__ x, const float* __restrict__ basis,
    const float* __restrict__ wgmax, float* __restrict__ out)
{
    __shared__ float D[64];
    __shared__ unsigned int hist[NUM_BINS * HREP];   // 4 KiB
    __shared__ float wred[4];
    __shared__ float s_scale;
    if (threadIdx.x < 64) D[threadIdx.x] = basis[threadIdx.x];
    for (int i = threadIdx.x; i < NUM_BINS * HREP; i += 256) hist[i] = 0;

    // reduce the 1536 per-WG maxima (L2-resident; ~6 loads/thread)
    float m = 0.0f;
    for (int i = threadIdx.x; i < NWG1; i += 256) m = fmaxf(m, wgmax[i]);
    #pragma unroll
    for (int off = 32; off > 0; off >>= 1)
        m = fmaxf(m, __shfl_down(m, off, 64));
    if ((threadIdx.x & 63) == 0) wred[threadIdx.x >> 6] = m;
    __syncthreads();
    if (threadIdx.x == 0) {
        float mm = fmaxf(fmaxf(wred[0], wred[1]), fmaxf(wred[2], wred[3]));
        s_scale = (float)NUM_BINS / (mm * 1.1f);
    }
    __syncthreads();

    float scale = s_scale;
    int   sub   = threadIdx.x & (HREP - 1);
    int   bc    = blockIdx.x >> 4;              // 16 WGs per (b,c)
    int   n     = (blockIdx.x & 15) * 256 + threadIdx.x;
    int   hb    = n >> 6, wb = n & 63;
    const float* p = x + ((size_t)bc << 18) + ((size_t)(hb * 8) << 9) + (size_t)(wb * 8);

    float blk[64];
    load_block(p, blk);
    dct_block(D, blk, [&](float mag) {
        int bin = (int)(mag * scale);           // mag >= 0: trunc == floor
        bin = min(bin, NUM_BINS - 1);
        atomicAdd(&hist[bin * HREP + sub], 1u);
    });
    __syncthreads();

    if (threadIdx.x < NUM_BINS) {
        unsigned int c = 0;
        #pragma unroll
        for (int r = 0; r < HREP; ++r) c += hist[threadIdx.x * HREP + r];
        // counts <= 2^18, /2^18 -> dyadic, 16-way float atomic sum is exact
        atomicAdd(&out[bc * NUM_BINS + threadIdx.x], (float)c * (1.0f / 262144.0f));
    }
}

extern "C" void kernel_launch(void* const* d_in, const int* in_sizes, int n_in,
                              void* d_out, int out_size, void* d_ws, size_t ws_size,
                              hipStream_t stream) {
    const float* x     = (const float*)d_in[0];
    const float* basis = (const float*)d_in[1];
    float* out         = (float*)d_out;
    float* wgmax       = (float*)d_ws;

    dct_max_kernel <<<NWG1, 256, 0, stream>>>(x, basis, wgmax, out);
    dct_hist_kernel<<<NWG1, 256, 0, stream>>>(x, basis, wgmax, out);
}